// Round 1
// baseline (704.740 us; speedup 1.0000x reference)
//
#include <hip/hip_runtime.h>
#include <hip/hip_bf16.h>
#include <cstdint>
#include <cstddef>

typedef __bf16 bf16_t;
typedef __bf16 bf16x8 __attribute__((ext_vector_type(8)));
typedef __bf16 bf16x4v __attribute__((ext_vector_type(4)));
typedef float f32x4 __attribute__((ext_vector_type(4)));

#define SCALE_Q 0.17677669529663687f

// ---------------- conversions ----------------

__global__ void conv_x_kernel(const float* __restrict__ x, bf16_t* __restrict__ xb, int n4) {
  int i = blockIdx.x * blockDim.x + threadIdx.x;
  int stride = gridDim.x * blockDim.x;
  const float4* xv = (const float4*)x;
  for (; i < n4; i += stride) {
    float4 v = xv[i];
    bf16x4v o;
    o[0] = (bf16_t)v.x; o[1] = (bf16_t)v.y; o[2] = (bf16_t)v.z; o[3] = (bf16_t)v.w;
    *(bf16x4v*)(xb + (size_t)i * 4) = o;
  }
}

// transposes weights to n-major bf16 and builds combined (rel_bias + mask) table
__global__ void conv_small_kernel(const float* __restrict__ w_qkv, const float* __restrict__ w_out,
                                  const float* __restrict__ bias_table, const float* __restrict__ mask,
                                  bf16_t* __restrict__ wqkvt, bf16_t* __restrict__ woutt,
                                  float* __restrict__ rbm) {
  const int N1 = 1152 * 384;            // wqkvt elems
  const int N2 = 384 * 384;             // woutt elems
  const int N3 = 64 * 12 * 2401;        // rbm elems
  int i = blockIdx.x * blockDim.x + threadIdx.x;
  int stride = gridDim.x * blockDim.x;
  for (; i < N1 + N2 + N3; i += stride) {
    if (i < N1) {
      int n = i / 384, k = i - n * 384;
      wqkvt[i] = (bf16_t)w_qkv[k * 1152 + n];
    } else if (i < N1 + N2) {
      int j = i - N1;
      int n = j / 384, k = j - n * 384;
      woutt[j] = (bf16_t)w_out[k * 384 + n];
    } else {
      int j = i - (N1 + N2);
      int w = j / 28812; int rem = j - w * 28812;
      int h = rem / 2401; int ij = rem - h * 2401;
      int ii = ij / 49; int jj = ij - ii * 49;
      int ci = (ii / 7) * 13 + (ii % 7);
      int j48 = 48 - jj;
      int cj = (j48 / 7) * 13 + (j48 % 7);
      rbm[j] = bias_table[(ci + cj) * 12 + h] + mask[w * 2401 + ij];
    }
  }
}

// ---------------- qkv GEMM: [100352 x 384] @ [384 x 1152] -> scatter Q/K/V head-major bf16 ----------------

__global__ __launch_bounds__(256) void gemm_qkv_kernel(const bf16_t* __restrict__ A,
                                                       const bf16_t* __restrict__ Bt,
                                                       bf16_t* __restrict__ Q, bf16_t* __restrict__ K,
                                                       bf16_t* __restrict__ V) {
  __shared__ bf16_t As[128 * 32];
  __shared__ bf16_t Bs[128 * 32];
  int bm = blockIdx.x, bn = blockIdx.y;
  int t = threadIdx.x;
  int lane = t & 63, w = t >> 6, wr = w >> 1, wc = w & 1;
  int m0 = bm * 128, n0 = bn * 128;

  int abase[2], bbase[2];
#pragma unroll
  for (int q = 0; q < 2; ++q) {
    int idx8 = q * 256 + t;
    int r = idx8 >> 2, ko = (idx8 & 3) << 3;
    abase[q] = (m0 + r) * 384 + ko;
    bbase[q] = (n0 + r) * 384 + ko;
  }

  f32x4 acc[4][4] = {};
  int lr = lane & 15, lg = lane >> 4;
  for (int kt = 0; kt < 12; ++kt) {
    int k0 = kt * 32;
#pragma unroll
    for (int q = 0; q < 2; ++q) {
      int idx8 = q * 256 + t;
      *(uint4*)(&As[idx8 * 8]) = *(const uint4*)(&A[abase[q] + k0]);
      *(uint4*)(&Bs[idx8 * 8]) = *(const uint4*)(&Bt[bbase[q] + k0]);
    }
    __syncthreads();
    bf16x8 af[4], bfv[4];
#pragma unroll
    for (int mi = 0; mi < 4; ++mi) af[mi] = *(const bf16x8*)(&As[(wr * 64 + mi * 16 + lr) * 32 + lg * 8]);
#pragma unroll
    for (int ni = 0; ni < 4; ++ni) bfv[ni] = *(const bf16x8*)(&Bs[(wc * 64 + ni * 16 + lr) * 32 + lg * 8]);
#pragma unroll
    for (int mi = 0; mi < 4; ++mi)
#pragma unroll
      for (int ni = 0; ni < 4; ++ni)
        acc[mi][ni] = __builtin_amdgcn_mfma_f32_16x16x32_bf16(af[mi], bfv[ni], acc[mi][ni], 0, 0, 0);
    __syncthreads();
  }

  // epilogue: scatter to head-major Q/K/V, scale Q
#pragma unroll
  for (int mi = 0; mi < 4; ++mi)
#pragma unroll
    for (int ni = 0; ni < 4; ++ni) {
      int c = n0 + wc * 64 + ni * 16 + lr;
      int part = c / 384;
      int cc = c - part * 384;
      int h = cc >> 5, d = cc & 31;
      bf16_t* dst = (part == 0) ? Q : ((part == 1) ? K : V);
      float sc = (part == 0) ? SCALE_Q : 1.0f;
#pragma unroll
      for (int rg = 0; rg < 4; ++rg) {
        int m = m0 + wr * 64 + mi * 16 + lg * 4 + rg;
        int b = m / 49; int n = m - b * 49;
        dst[((size_t)(b * 12 + h) * 49 + n) * 32 + d] = (bf16_t)(acc[mi][ni][rg] * sc);
      }
    }
}

// ---------------- attention: one wave per (b,h) ----------------

__global__ __launch_bounds__(64) void attn_kernel(bf16_t* Qio, const bf16_t* __restrict__ Kb,
                                                  const bf16_t* __restrict__ Vb,
                                                  const float* __restrict__ rbm) {
  __shared__ float tbl[49 * 49];
  __shared__ bf16_t Pl[64 * 72];
  __shared__ bf16_t Vt[32 * 72];
  int bh = blockIdx.x;            // b*12 + h
  int b = bh / 12, h = bh - b * 12;
  int w = b & 63;
  int t = threadIdx.x;
  int lr = t & 15, lg = t >> 4;

  const float* tsrc = rbm + (size_t)(w * 12 + h) * 2401;
  for (int i = t; i < 2401; i += 64) tbl[i] = tsrc[i];
  for (int i = t; i < 32 * 72; i += 64) Vt[i] = (bf16_t)0.0f;
  __syncthreads();

  // stage V transposed: Vt[d][key]
  const bf16_t* vb = Vb + (size_t)bh * 1568;
  for (int ch = t; ch < 196; ch += 64) {
    int row = ch >> 2; int d8 = (ch & 3) << 3;
    bf16x8 vv = *(const bf16x8*)(&vb[row * 32 + d8]);
#pragma unroll
    for (int j = 0; j < 8; ++j) Vt[(d8 + j) * 72 + row] = vv[j];
  }

  // Q and K fragments straight from global (row = lane&15, k = (lane>>4)*8)
  const bf16_t* qb = Qio + (size_t)bh * 1568;
  const bf16_t* kb = Kb + (size_t)bh * 1568;
  bf16x8 aq[4], ak[4];
#pragma unroll
  for (int ti = 0; ti < 4; ++ti) { int r = ti * 16 + lr; if (r > 48) r = 48; aq[ti] = *(const bf16x8*)(&qb[r * 32 + lg * 8]); }
#pragma unroll
  for (int tj = 0; tj < 4; ++tj) { int r = tj * 16 + lr; if (r > 48) r = 48; ak[tj] = *(const bf16x8*)(&kb[r * 32 + lg * 8]); }

  // S = Q @ K^T  (DH=32 = one K-step)
  f32x4 s[4][4];
#pragma unroll
  for (int ti = 0; ti < 4; ++ti)
#pragma unroll
    for (int tj = 0; tj < 4; ++tj) {
      f32x4 z = {};
      s[ti][tj] = __builtin_amdgcn_mfma_f32_16x16x32_bf16(aq[ti], ak[tj], z, 0, 0, 0);
    }

  // + rel_bias + mask; pad cols -> -1e30
#pragma unroll
  for (int ti = 0; ti < 4; ++ti)
#pragma unroll
    for (int tj = 0; tj < 4; ++tj)
#pragma unroll
      for (int rg = 0; rg < 4; ++rg) {
        int i = ti * 16 + lg * 4 + rg;
        int j = tj * 16 + lr;
        int ic = i < 49 ? i : 48;
        float add = (j < 49) ? tbl[ic * 49 + j] : -1e30f;
        s[ti][tj][rg] += add;
      }

  // row softmax (rows live in (ti, rg) per lane; reduce over tj regs + 16 lanes)
  float rs[4][4];
#pragma unroll
  for (int ti = 0; ti < 4; ++ti)
#pragma unroll
    for (int rg = 0; rg < 4; ++rg) {
      float mx = fmaxf(fmaxf(s[ti][0][rg], s[ti][1][rg]), fmaxf(s[ti][2][rg], s[ti][3][rg]));
#pragma unroll
      for (int off = 1; off < 16; off <<= 1) mx = fmaxf(mx, __shfl_xor(mx, off));
      float sm = 0.f;
#pragma unroll
      for (int tj = 0; tj < 4; ++tj) {
        float p = __expf(s[ti][tj][rg] - mx);
        s[ti][tj][rg] = p;
        sm += p;
      }
#pragma unroll
      for (int off = 1; off < 16; off <<= 1) sm += __shfl_xor(sm, off);
      rs[ti][rg] = 1.0f / sm;
    }

  // P -> LDS (bf16, unnormalized), padded stride 72
#pragma unroll
  for (int ti = 0; ti < 4; ++ti)
#pragma unroll
    for (int tj = 0; tj < 4; ++tj)
#pragma unroll
      for (int rg = 0; rg < 4; ++rg) {
        int row = ti * 16 + lg * 4 + rg, col = tj * 16 + lr;
        Pl[row * 72 + col] = (bf16_t)s[ti][tj][rg];
      }
  __syncthreads();

  // O = P @ V
  f32x4 o[4][2] = {};
#pragma unroll
  for (int ks = 0; ks < 2; ++ks) {
    bf16x8 bv[2];
#pragma unroll
    for (int tn = 0; tn < 2; ++tn) bv[tn] = *(const bf16x8*)(&Vt[(tn * 16 + lr) * 72 + ks * 32 + lg * 8]);
#pragma unroll
    for (int ti = 0; ti < 4; ++ti) {
      bf16x8 ap = *(const bf16x8*)(&Pl[(ti * 16 + lr) * 72 + ks * 32 + lg * 8]);
#pragma unroll
      for (int tn = 0; tn < 2; ++tn)
        o[ti][tn] = __builtin_amdgcn_mfma_f32_16x16x32_bf16(ap, bv[tn], o[ti][tn], 0, 0, 0);
    }
  }

  // normalize by row sum, overwrite Q slot with output (bf16)
  bf16_t* ob = Qio + (size_t)bh * 1568;
#pragma unroll
  for (int ti = 0; ti < 4; ++ti)
#pragma unroll
    for (int tn = 0; tn < 2; ++tn)
#pragma unroll
      for (int rg = 0; rg < 4; ++rg) {
        int row = ti * 16 + lg * 4 + rg;
        if (row < 49) {
          int d = tn * 16 + lr;
          ob[row * 32 + d] = (bf16_t)(o[ti][tn][rg] * rs[ti][rg]);
        }
      }
}

// ---------------- out projection: [100352 x 384] @ [384 x 384] + b_out -> fp32 ----------------

__global__ __launch_bounds__(256) void gemm_out_kernel(const bf16_t* __restrict__ O,
                                                       const bf16_t* __restrict__ Bt,
                                                       const float* __restrict__ bias,
                                                       float* __restrict__ C) {
  __shared__ bf16_t As[128 * 32];
  __shared__ bf16_t Bs[128 * 32];
  int bm = blockIdx.x, bn = blockIdx.y;
  int t = threadIdx.x;
  int lane = t & 63, w = t >> 6, wr = w >> 1, wc = w & 1;
  int m0 = bm * 128, n0 = bn * 128;

  int abase[2], bbase[2];
#pragma unroll
  for (int q = 0; q < 2; ++q) {
    int idx8 = q * 256 + t;
    int r = idx8 >> 2, ko = (idx8 & 3) << 3;
    int m = m0 + r;
    int b = m / 49, n = m - b * 49;
    abase[q] = b * 18816 + n * 32 + ko;   // + kt*1568 per step (head-major O)
    bbase[q] = (n0 + r) * 384 + ko;
  }

  f32x4 acc[4][4] = {};
  int lr = lane & 15, lg = lane >> 4;
  for (int kt = 0; kt < 12; ++kt) {
#pragma unroll
    for (int q = 0; q < 2; ++q) {
      int idx8 = q * 256 + t;
      *(uint4*)(&As[idx8 * 8]) = *(const uint4*)(&O[abase[q] + kt * 1568]);
      *(uint4*)(&Bs[idx8 * 8]) = *(const uint4*)(&Bt[bbase[q] + kt * 32]);
    }
    __syncthreads();
    bf16x8 af[4], bfv[4];
#pragma unroll
    for (int mi = 0; mi < 4; ++mi) af[mi] = *(const bf16x8*)(&As[(wr * 64 + mi * 16 + lr) * 32 + lg * 8]);
#pragma unroll
    for (int ni = 0; ni < 4; ++ni) bfv[ni] = *(const bf16x8*)(&Bs[(wc * 64 + ni * 16 + lr) * 32 + lg * 8]);
#pragma unroll
    for (int mi = 0; mi < 4; ++mi)
#pragma unroll
      for (int ni = 0; ni < 4; ++ni)
        acc[mi][ni] = __builtin_amdgcn_mfma_f32_16x16x32_bf16(af[mi], bfv[ni], acc[mi][ni], 0, 0, 0);
    __syncthreads();
  }

#pragma unroll
  for (int mi = 0; mi < 4; ++mi)
#pragma unroll
    for (int ni = 0; ni < 4; ++ni) {
      int c = n0 + wc * 64 + ni * 16 + lr;
      float bo = bias[c];
#pragma unroll
      for (int rg = 0; rg < 4; ++rg) {
        int m = m0 + wr * 64 + mi * 16 + lg * 4 + rg;
        C[(size_t)m * 384 + c] = acc[mi][ni][rg] + bo;
      }
    }
}

// ---------------- host ----------------

extern "C" void kernel_launch(void* const* d_in, const int* in_sizes, int n_in,
                              void* d_out, int out_size, void* d_ws, size_t ws_size,
                              hipStream_t stream) {
  const float* x          = (const float*)d_in[0];
  const float* mask       = (const float*)d_in[1];
  const float* w_qkv      = (const float*)d_in[2];
  const float* bias_table = (const float*)d_in[3];
  const float* w_out      = (const float*)d_in[4];
  const float* b_out      = (const float*)d_in[5];
  float* out = (float*)d_out;

  const size_t XE = 38535168ULL;  // 2048*49*384
  char* ws = (char*)d_ws;
  size_t off = 0;
  auto alloc = [&](size_t bytes) { void* p = ws + off; off += (bytes + 255) & ~(size_t)255; return p; };
  bf16_t* xb    = (bf16_t*)alloc(XE * 2);
  bf16_t* wqkvt = (bf16_t*)alloc(442368ULL * 2);
  bf16_t* woutt = (bf16_t*)alloc(147456ULL * 2);
  float*  rbm   = (float*) alloc(1843968ULL * 4);
  bf16_t* Qb    = (bf16_t*)alloc(XE * 2);
  bf16_t* Kb    = (bf16_t*)alloc(XE * 2);
  bf16_t* Vb    = (bf16_t*)alloc(XE * 2);
  if (off > ws_size) return;  // workspace too small; fail loudly via absmax

  conv_x_kernel<<<2048, 256, 0, stream>>>(x, xb, (int)(XE / 4));
  conv_small_kernel<<<1188, 256, 0, stream>>>(w_qkv, w_out, bias_table, mask, wqkvt, woutt, rbm);
  gemm_qkv_kernel<<<dim3(784, 9), 256, 0, stream>>>(xb, wqkvt, Qb, Kb, Vb);
  attn_kernel<<<24576, 64, 0, stream>>>(Qb, Kb, Vb, rbm);
  gemm_out_kernel<<<dim3(784, 3), 256, 0, stream>>>(Qb, woutt, b_out, out);
}

// Round 2
// 631.324 us; speedup vs baseline: 1.1163x; 1.1163x over previous
//
#include <hip/hip_runtime.h>
#include <hip/hip_bf16.h>
#include <cstdint>
#include <cstddef>

typedef __bf16 bf16_t;
typedef __bf16 bf16x8 __attribute__((ext_vector_type(8)));
typedef __bf16 bf16x4v __attribute__((ext_vector_type(4)));
typedef float f32x4 __attribute__((ext_vector_type(4)));

#define SCALE_Q 0.17677669529663687f

// async global->LDS, 16B per lane (CK-style addrspace casts)
typedef const __attribute__((address_space(1))) unsigned int* gas1;
typedef __attribute__((address_space(3))) unsigned int* las3;
__device__ __forceinline__ void gload16(const bf16_t* g, bf16_t* l) {
  __builtin_amdgcn_global_load_lds((gas1)(const void*)g, (las3)(void*)l, 16, 0, 0);
}

// ---------------- conversions ----------------

__global__ void conv_x_kernel(const float* __restrict__ x, bf16_t* __restrict__ xb, int n4) {
  int i = blockIdx.x * blockDim.x + threadIdx.x;
  int stride = gridDim.x * blockDim.x;
  const float4* xv = (const float4*)x;
  for (; i < n4; i += stride) {
    float4 v = xv[i];
    bf16x4v o;
    o[0] = (bf16_t)v.x; o[1] = (bf16_t)v.y; o[2] = (bf16_t)v.z; o[3] = (bf16_t)v.w;
    *(bf16x4v*)(xb + (size_t)i * 4) = o;
  }
}

__global__ void conv_small_kernel(const float* __restrict__ w_qkv, const float* __restrict__ w_out,
                                  const float* __restrict__ bias_table, const float* __restrict__ mask,
                                  bf16_t* __restrict__ wqkvt, bf16_t* __restrict__ woutt,
                                  float* __restrict__ rbm) {
  const int N1 = 1152 * 384;
  const int N2 = 384 * 384;
  const int N3 = 64 * 12 * 2401;
  int i = blockIdx.x * blockDim.x + threadIdx.x;
  int stride = gridDim.x * blockDim.x;
  for (; i < N1 + N2 + N3; i += stride) {
    if (i < N1) {
      int n = i / 384, k = i - n * 384;
      wqkvt[i] = (bf16_t)w_qkv[k * 1152 + n];
    } else if (i < N1 + N2) {
      int j = i - N1;
      int n = j / 384, k = j - n * 384;
      woutt[j] = (bf16_t)w_out[k * 384 + n];
    } else {
      int j = i - (N1 + N2);
      int w = j / 28812; int rem = j - w * 28812;
      int h = rem / 2401; int ij = rem - h * 2401;
      int ii = ij / 49; int jj = ij - ii * 49;
      int ci = (ii / 7) * 13 + (ii % 7);
      int j48 = 48 - jj;
      int cj = (j48 / 7) * 13 + (j48 % 7);
      rbm[j] = bias_table[(ci + cj) * 12 + h] + mask[w * 2401 + ij];
    }
  }
}

// ---------------- qkv GEMM: [100352 x 384] @ [384 x 1152] -> head-major Q/K/V ----------------

__global__ __launch_bounds__(256) void gemm_qkv_kernel(const bf16_t* __restrict__ A,
                                                       const bf16_t* __restrict__ Bt,
                                                       bf16_t* __restrict__ Q, bf16_t* __restrict__ K,
                                                       bf16_t* __restrict__ V) {
  __shared__ __align__(16) bf16_t As[128 * 32];
  __shared__ __align__(16) bf16_t Bs[128 * 32];
  int bid = blockIdx.x;
  int nb = (bid & 7) * 882 + (bid >> 3);   // XCD-chunked (7056 = 8*882)
  int bm = nb / 9, bn = nb - bm * 9;       // bn-fast: A-panel reuse within XCD
  int t = threadIdx.x;
  int lane = t & 63, w = t >> 6, wr = w >> 1, wc = w & 1;
  int m0 = bm * 128, n0 = bn * 128;

  int abase[2], bbase[2];
#pragma unroll
  for (int q = 0; q < 2; ++q) {
    int idx8 = q * 256 + t;
    int r = idx8 >> 2, ko = (idx8 & 3) << 3;
    abase[q] = (m0 + r) * 384 + ko;
    bbase[q] = (n0 + r) * 384 + ko;
  }

  f32x4 acc[4][4] = {};
  int lr = lane & 15, lg = lane >> 4;
  for (int kt = 0; kt < 12; ++kt) {
    int k0 = kt * 32;
    gload16(&A[abase[0] + k0], &As[t * 8]);
    gload16(&A[abase[1] + k0], &As[(256 + t) * 8]);
    gload16(&Bt[bbase[0] + k0], &Bs[t * 8]);
    gload16(&Bt[bbase[1] + k0], &Bs[(256 + t) * 8]);
    __syncthreads();
    bf16x8 af[4], bfv[4];
#pragma unroll
    for (int mi = 0; mi < 4; ++mi) af[mi] = *(const bf16x8*)(&As[(wr * 64 + mi * 16 + lr) * 32 + lg * 8]);
#pragma unroll
    for (int ni = 0; ni < 4; ++ni) bfv[ni] = *(const bf16x8*)(&Bs[(wc * 64 + ni * 16 + lr) * 32 + lg * 8]);
#pragma unroll
    for (int mi = 0; mi < 4; ++mi)
#pragma unroll
      for (int ni = 0; ni < 4; ++ni)
        acc[mi][ni] = __builtin_amdgcn_mfma_f32_16x16x32_bf16(af[mi], bfv[ni], acc[mi][ni], 0, 0, 0);
    __syncthreads();
  }

#pragma unroll
  for (int mi = 0; mi < 4; ++mi)
#pragma unroll
    for (int ni = 0; ni < 4; ++ni) {
      int c = n0 + wc * 64 + ni * 16 + lr;
      int part = c / 384;
      int cc = c - part * 384;
      int h = cc >> 5, d = cc & 31;
      bf16_t* dst = (part == 0) ? Q : ((part == 1) ? K : V);
      float sc = (part == 0) ? SCALE_Q : 1.0f;
#pragma unroll
      for (int rg = 0; rg < 4; ++rg) {
        int m = m0 + wr * 64 + mi * 16 + lg * 4 + rg;
        int b = m / 49; int n = m - b * 49;
        dst[((size_t)(b * 12 + h) * 49 + n) * 32 + d] = (bf16_t)(acc[mi][ni][rg] * sc);
      }
    }
}

// ---------------- attention: block = one (w,h); 2 waves x 16 batches ----------------

__global__ __launch_bounds__(128) void attn_kernel(bf16_t* Qio, const bf16_t* __restrict__ Kb,
                                                   const bf16_t* __restrict__ Vb,
                                                   const float* __restrict__ rbm) {
  __shared__ float tbl[2401];
  __shared__ __align__(16) bf16_t Pl[2][64 * 72];
  __shared__ __align__(16) bf16_t Vt[2][32 * 72];
  int wh = blockIdx.x;                 // w*12 + h
  int t = threadIdx.x;
  int wv = t >> 6, lane = t & 63;
  int lr = lane & 15, lg = lane >> 4;
  int w = wh / 12, h = wh - w * 12;

  const float* tsrc = rbm + (size_t)wh * 2401;
  for (int i = t; i < 2401; i += 128) tbl[i] = tsrc[i];
  bf16_t* pl = Pl[wv];
  bf16_t* vt = Vt[wv];
  for (int i = lane; i < 32 * 24; i += 64) {   // zero V pad cols 48..71 once
    int r = i / 24, c = 48 + (i - (i / 24) * 24);
    vt[r * 72 + c] = (bf16_t)0.0f;
  }
  __syncthreads();

  for (int it = 0; it < 16; ++it) {
    int b = w + 64 * (wv * 16 + it);
    size_t bh = (size_t)b * 12 + h;
    const bf16_t* qb = Qio + bh * 1568;
    const bf16_t* kb = Kb + bh * 1568;
    const bf16_t* vb = Vb + bh * 1568;

    // stage V transposed: vt[d][key]
    for (int ch = lane; ch < 196; ch += 64) {
      int row = ch >> 2; int d8 = (ch & 3) << 3;
      bf16x8 vv = *(const bf16x8*)(&vb[row * 32 + d8]);
#pragma unroll
      for (int j = 0; j < 8; ++j) vt[(d8 + j) * 72 + row] = vv[j];
    }

    bf16x8 aq[4], ak[4];
#pragma unroll
    for (int ti = 0; ti < 4; ++ti) {
      int r = ti * 16 + lr; if (r > 48) r = 48;
      aq[ti] = *(const bf16x8*)(&qb[r * 32 + lg * 8]);
      ak[ti] = *(const bf16x8*)(&kb[r * 32 + lg * 8]);
    }

    f32x4 s[4][4];
#pragma unroll
    for (int ti = 0; ti < 4; ++ti)
#pragma unroll
      for (int tj = 0; tj < 4; ++tj) {
        f32x4 z = {};
        s[ti][tj] = __builtin_amdgcn_mfma_f32_16x16x32_bf16(aq[ti], ak[tj], z, 0, 0, 0);
      }

#pragma unroll
    for (int ti = 0; ti < 4; ++ti)
#pragma unroll
      for (int tj = 0; tj < 4; ++tj)
#pragma unroll
        for (int rg = 0; rg < 4; ++rg) {
          int i = ti * 16 + lg * 4 + rg;
          int j = tj * 16 + lr;
          int ic = i < 49 ? i : 48;
          float add = (j < 49) ? tbl[ic * 49 + j] : -1e30f;
          s[ti][tj][rg] += add;
        }

    float rs[4][4];
#pragma unroll
    for (int ti = 0; ti < 4; ++ti)
#pragma unroll
      for (int rg = 0; rg < 4; ++rg) {
        float mx = fmaxf(fmaxf(s[ti][0][rg], s[ti][1][rg]), fmaxf(s[ti][2][rg], s[ti][3][rg]));
#pragma unroll
        for (int off = 1; off < 16; off <<= 1) mx = fmaxf(mx, __shfl_xor(mx, off));
        float sm = 0.f;
#pragma unroll
        for (int tj = 0; tj < 4; ++tj) {
          float p = __expf(s[ti][tj][rg] - mx);
          s[ti][tj][rg] = p;
          sm += p;
        }
#pragma unroll
        for (int off = 1; off < 16; off <<= 1) sm += __shfl_xor(sm, off);
        rs[ti][rg] = 1.0f / sm;
      }

#pragma unroll
    for (int ti = 0; ti < 4; ++ti)
#pragma unroll
      for (int tj = 0; tj < 4; ++tj)
#pragma unroll
        for (int rg = 0; rg < 4; ++rg) {
          int row = ti * 16 + lg * 4 + rg, col = tj * 16 + lr;
          pl[row * 72 + col] = (bf16_t)s[ti][tj][rg];
        }
    asm volatile("s_waitcnt lgkmcnt(0)" ::: "memory");

    f32x4 o[4][2] = {};
#pragma unroll
    for (int ks = 0; ks < 2; ++ks) {
      bf16x8 bv[2];
#pragma unroll
      for (int tn = 0; tn < 2; ++tn) bv[tn] = *(const bf16x8*)(&vt[(tn * 16 + lr) * 72 + ks * 32 + lg * 8]);
#pragma unroll
      for (int ti = 0; ti < 4; ++ti) {
        bf16x8 ap = *(const bf16x8*)(&pl[(ti * 16 + lr) * 72 + ks * 32 + lg * 8]);
#pragma unroll
        for (int tn = 0; tn < 2; ++tn)
          o[ti][tn] = __builtin_amdgcn_mfma_f32_16x16x32_bf16(ap, bv[tn], o[ti][tn], 0, 0, 0);
      }
    }

    bf16_t* ob = Qio + bh * 1568;
#pragma unroll
    for (int ti = 0; ti < 4; ++ti)
#pragma unroll
      for (int tn = 0; tn < 2; ++tn)
#pragma unroll
        for (int rg = 0; rg < 4; ++rg) {
          int row = ti * 16 + lg * 4 + rg;
          if (row < 49) {
            int d = tn * 16 + lr;
            ob[row * 32 + d] = (bf16_t)(o[ti][tn][rg] * rs[ti][rg]);
          }
        }
  }
}

// ---------------- out projection: [100352 x 384] @ [384 x 384] + b_out -> fp32 ----------------

__global__ __launch_bounds__(256) void gemm_out_kernel(const bf16_t* __restrict__ O,
                                                       const bf16_t* __restrict__ Bt,
                                                       const float* __restrict__ bias,
                                                       float* __restrict__ C) {
  __shared__ __align__(16) bf16_t As[128 * 32];
  __shared__ __align__(16) bf16_t Bs[128 * 32];
  int bid = blockIdx.x;
  int nb = (bid & 7) * 294 + (bid >> 3);   // 2352 = 8*294
  int bm = nb / 3, bn = nb - bm * 3;
  int t = threadIdx.x;
  int lane = t & 63, w = t >> 6, wr = w >> 1, wc = w & 1;
  int m0 = bm * 128, n0 = bn * 128;

  int abase[2], bbase[2];
#pragma unroll
  for (int q = 0; q < 2; ++q) {
    int idx8 = q * 256 + t;
    int r = idx8 >> 2, ko = (idx8 & 3) << 3;
    int m = m0 + r;
    int b = m / 49, n = m - b * 49;
    abase[q] = b * 18816 + n * 32 + ko;
    bbase[q] = (n0 + r) * 384 + ko;
  }

  f32x4 acc[4][4] = {};
  int lr = lane & 15, lg = lane >> 4;
  for (int kt = 0; kt < 12; ++kt) {
    gload16(&O[abase[0] + kt * 1568], &As[t * 8]);
    gload16(&O[abase[1] + kt * 1568], &As[(256 + t) * 8]);
    gload16(&Bt[bbase[0] + kt * 32], &Bs[t * 8]);
    gload16(&Bt[bbase[1] + kt * 32], &Bs[(256 + t) * 8]);
    __syncthreads();
    bf16x8 af[4], bfv[4];
#pragma unroll
    for (int mi = 0; mi < 4; ++mi) af[mi] = *(const bf16x8*)(&As[(wr * 64 + mi * 16 + lr) * 32 + lg * 8]);
#pragma unroll
    for (int ni = 0; ni < 4; ++ni) bfv[ni] = *(const bf16x8*)(&Bs[(wc * 64 + ni * 16 + lr) * 32 + lg * 8]);
#pragma unroll
    for (int mi = 0; mi < 4; ++mi)
#pragma unroll
      for (int ni = 0; ni < 4; ++ni)
        acc[mi][ni] = __builtin_amdgcn_mfma_f32_16x16x32_bf16(af[mi], bfv[ni], acc[mi][ni], 0, 0, 0);
    __syncthreads();
  }

#pragma unroll
  for (int mi = 0; mi < 4; ++mi)
#pragma unroll
    for (int ni = 0; ni < 4; ++ni) {
      int c = n0 + wc * 64 + ni * 16 + lr;
      float bo = bias[c];
#pragma unroll
      for (int rg = 0; rg < 4; ++rg) {
        int m = m0 + wr * 64 + mi * 16 + lg * 4 + rg;
        C[(size_t)m * 384 + c] = acc[mi][ni][rg] + bo;
      }
    }
}

// ---------------- host ----------------

extern "C" void kernel_launch(void* const* d_in, const int* in_sizes, int n_in,
                              void* d_out, int out_size, void* d_ws, size_t ws_size,
                              hipStream_t stream) {
  const float* x          = (const float*)d_in[0];
  const float* mask       = (const float*)d_in[1];
  const float* w_qkv      = (const float*)d_in[2];
  const float* bias_table = (const float*)d_in[3];
  const float* w_out      = (const float*)d_in[4];
  const float* b_out      = (const float*)d_in[5];
  float* out = (float*)d_out;

  const size_t XE = 38535168ULL;  // 2048*49*384
  char* ws = (char*)d_ws;
  size_t off = 0;
  auto alloc = [&](size_t bytes) { void* p = ws + off; off += (bytes + 255) & ~(size_t)255; return p; };
  bf16_t* xb    = (bf16_t*)alloc(XE * 2);
  bf16_t* wqkvt = (bf16_t*)alloc(442368ULL * 2);
  bf16_t* woutt = (bf16_t*)alloc(147456ULL * 2);
  float*  rbm   = (float*) alloc(1843968ULL * 4);
  bf16_t* Qb    = (bf16_t*)alloc(XE * 2);
  bf16_t* Kb    = (bf16_t*)alloc(XE * 2);
  bf16_t* Vb    = (bf16_t*)alloc(XE * 2);
  if (off > ws_size) return;

  conv_x_kernel<<<2048, 256, 0, stream>>>(x, xb, (int)(XE / 4));
  conv_small_kernel<<<1188, 256, 0, stream>>>(w_qkv, w_out, bias_table, mask, wqkvt, woutt, rbm);
  gemm_qkv_kernel<<<7056, 256, 0, stream>>>(xb, wqkvt, Qb, Kb, Vb);
  attn_kernel<<<768, 128, 0, stream>>>(Qb, Kb, Vb, rbm);
  gemm_out_kernel<<<2352, 256, 0, stream>>>(Qb, woutt, b_out, out);
}